// Round 8
// baseline (265.939 us; speedup 1.0000x reference)
//
#include <hip/hip_runtime.h>
#include <hip/hip_bf16.h>

#define S_LEN 2048
#define HIDN  2048
#define NH    16
#define NKV   8
#define DH    128

typedef __bf16 bf16_t;
typedef __bf16 bf16x4 __attribute__((ext_vector_type(4)));
typedef __bf16 bf16x8 __attribute__((ext_vector_type(8)));
typedef float  floatx4 __attribute__((ext_vector_type(4)));

#define NEG_BIG (-1.0e30f)

#define BM 128
#define BN 128
#define BK 64
#define TILE (BM * BK)

// async global->LDS, 16B per lane. LDS dest must be wave-uniform base + lane*16.
__device__ __forceinline__ void g2l16(const bf16_t* g, bf16_t* l) {
  __builtin_amdgcn_global_load_lds(
      (const __attribute__((address_space(1))) unsigned int*)g,
      (__attribute__((address_space(3))) unsigned int*)l, 16, 0, 0);
}

// ---------------- GEMM tile: f32 inputs, VGPR-convert staging, LDS dbuf ------
// C[m0+..][n0+..] = A[M,K] * Bt[N,K]^T, f32 row-major, row stride K.
// K-loop: st(buf) -> barrier -> prefetch(k+1) -> MFMA(buf). One barrier/iter;
// prefetch loads stay in flight across the MFMA phase (issued after barrier).
// As/Bs are 2*TILE each (double-buffered), 16B-chunk XOR swizzle c^(row&7).
__device__ __forceinline__ void gemm_tile_f32(
    const float* __restrict__ A, const float* __restrict__ Bt,
    int K, int m0, int n0, floatx4 acc[4][4], bf16_t* As, bf16_t* Bs)
{
  const int tid  = threadIdx.x;
  const int lane = tid & 63;
  const int wave = tid >> 6;
  const int wm = (wave & 1) << 6;
  const int wn = (wave >> 1) << 6;
  const int lr = lane & 15;
  const int lq = lane >> 4;

  #pragma unroll
  for (int i = 0; i < 4; ++i)
    #pragma unroll
    for (int j = 0; j < 4; ++j)
      acc[i][j] = floatx4{0.f, 0.f, 0.f, 0.f};

  floatx4 ra[4][2], rb[4][2];
  auto ld = [&](int k0) {
    #pragma unroll
    for (int it = 0; it < 4; ++it) {
      int linear = it * 256 + tid;          // 0..1023
      int row = linear >> 3;                // 128 rows
      int pc  = linear & 7;                 // physical chunk
      int c   = pc ^ (row & 7);             // logical chunk (swizzle)
      const float* pa = A  + (size_t)(m0 + row) * K + k0 + c * 8;
      const float* pb = Bt + (size_t)(n0 + row) * K + k0 + c * 8;
      ra[it][0] = *(const floatx4*)(pa);
      ra[it][1] = *(const floatx4*)(pa + 4);
      rb[it][0] = *(const floatx4*)(pb);
      rb[it][1] = *(const floatx4*)(pb + 4);
    }
  };
  auto st = [&](int buf) {
    #pragma unroll
    for (int it = 0; it < 4; ++it) {
      int linear = it * 256 + tid;
      bf16x8 va, vb;
      #pragma unroll
      for (int j = 0; j < 4; ++j) {
        va[j]     = (bf16_t)ra[it][0][j];
        va[4 + j] = (bf16_t)ra[it][1][j];
        vb[j]     = (bf16_t)rb[it][0][j];
        vb[4 + j] = (bf16_t)rb[it][1][j];
      }
      *(bf16x8*)(As + buf * TILE + linear * 8) = va;
      *(bf16x8*)(Bs + buf * TILE + linear * 8) = vb;
    }
  };

  ld(0);
  int kidx = 0;
  for (int k0 = 0; k0 < K; k0 += BK, ++kidx) {
    const int buf = kidx & 1;
    st(buf);
    __syncthreads();                         // ds_writes visible; prior buf reads done
    if (k0 + BK < K) ld(k0 + BK);            // in flight across MFMA phase
    const bf16_t* Ab = As + buf * TILE;
    const bf16_t* Bb = Bs + buf * TILE;
    #pragma unroll
    for (int kk = 0; kk < BK; kk += 32) {
      bf16x8 af[4], bfr[4];
      #pragma unroll
      for (int t = 0; t < 4; ++t) {
        int pcr = ((kk >> 3) + lq) ^ (lr & 7);
        af[t]  = *(const bf16x8*)(Ab + (wm + t * 16 + lr) * BK + pcr * 8);
        bfr[t] = *(const bf16x8*)(Bb + (wn + t * 16 + lr) * BK + pcr * 8);
      }
      #pragma unroll
      for (int i = 0; i < 4; ++i)
        #pragma unroll
        for (int j = 0; j < 4; ++j)
          acc[i][j] = __builtin_amdgcn_mfma_f32_16x16x32_bf16(af[i], bfr[j], acc[i][j], 0, 0, 0);
    }
  }
}

// QKV GEMM (f32 in) with fused RoPE (q,k) and V-transpose epilogue.
__global__ void __launch_bounds__(256, 2) gemm_qkv_kernel(
    const float* __restrict__ x, const float* __restrict__ Wq,
    const float* __restrict__ Wk, const float* __restrict__ Wv,
    bf16_t* __restrict__ qb, bf16_t* __restrict__ kb, bf16_t* __restrict__ vtb,
    const float* __restrict__ cosT, const float* __restrict__ sinT)
{
  __shared__ __align__(16) bf16_t As[2 * TILE];   // 32 KB (aliased by Epi below)
  __shared__ __align__(16) bf16_t Bs[2 * TILE];   // 32 KB
  const int tid = threadIdx.x;
  const int m0 = blockIdx.x * BM;
  const int nt = blockIdx.y;
  const float* Bt;
  int hbase;
  if (nt < 16)      { Bt = Wq + (size_t)nt * 128 * HIDN;        hbase = nt; }
  else if (nt < 24) { Bt = Wk + (size_t)(nt - 16) * 128 * HIDN; hbase = nt - 16; }
  else              { Bt = Wv + (size_t)(nt - 24) * 128 * HIDN; hbase = nt - 24; }

  floatx4 acc[4][4];
  gemm_tile_f32(x, Bt, HIDN, m0, 0, acc, As, Bs);

  __syncthreads();                           // all LDS reads done before Epi aliasing
  bf16_t* Epi = As;                          // 128*132 bf16 = 33 KB < 2*TILE(32KB)+...
  // NOTE: 128*132 = 16896 elements = 33 KB > As(32 KB); spill into Bs is fine
  // only if contiguous — As and Bs are separate arrays. Use stride 128 into As
  // (exactly 32 KB) instead; bank conflicts on the epilogue are tolerable.
  const int lane = tid & 63, wave = tid >> 6;
  const int wm = (wave & 1) << 6, wn = (wave >> 1) << 6;
  const int lr = lane & 15, lq = lane >> 4;
  #pragma unroll
  for (int i = 0; i < 4; ++i)
    #pragma unroll
    for (int j = 0; j < 4; ++j)
      #pragma unroll
      for (int r = 0; r < 4; ++r) {
        int row = wm + i * 16 + lq * 4 + r;
        int col = wn + j * 16 + lr;
        Epi[row * 128 + col] = (bf16_t)acc[i][j][r];
      }
  __syncthreads();

  if (nt < 24) {
    // RoPE: out[d] = a*cos - b*sin; out[d+64] = b*cos + a*sin (cos[d+64]==cos[d])
    bf16_t* outp = (nt < 16) ? qb : kb;
    #pragma unroll
    for (int u = 0; u < 32; ++u) {
      int idx = u * 256 + tid;              // 0..8191
      int dd = idx & 63, s = idx >> 6;
      float a = (float)Epi[s * 128 + dd];
      float b = (float)Epi[s * 128 + dd + 64];
      int sg = m0 + s;
      float cv = cosT[sg * DH + dd];
      float sv = sinT[sg * DH + dd];
      size_t off = ((size_t)hbase * S_LEN + sg) * DH;
      outp[off + dd]      = (bf16_t)(a * cv - b * sv);
      outp[off + dd + 64] = (bf16_t)(b * cv + a * sv);
    }
  } else {
    // V transpose: vt[hkv][d][s]
    bf16_t* dst = vtb + (size_t)hbase * DH * S_LEN;
    #pragma unroll
    for (int u = 0; u < 64; ++u) {
      int idx = u * 256 + tid;              // 0..16383
      int sl = idx & 127, d = idx >> 7;
      dst[(size_t)d * S_LEN + m0 + sl] = Epi[sl * 128 + d];
    }
  }
}

// out = ctx[2048,2048](bf16) * Wo^T(f32) -> d_out (f32).
// Mixed staging: ctx via g2l16 (bf16), Wo via VGPR-convert; both dbuf.
__global__ void __launch_bounds__(256, 2) gemm_out_kernel(
    const bf16_t* __restrict__ ctx, const float* __restrict__ Wo,
    float* __restrict__ out)
{
  __shared__ __align__(16) bf16_t As[2 * TILE];
  __shared__ __align__(16) bf16_t Bs[2 * TILE];
  const int tid = threadIdx.x;
  const int lane = tid & 63, wave = tid >> 6;
  const int wm = (wave & 1) << 6, wn = (wave >> 1) << 6;
  const int lr = lane & 15, lq = lane >> 4;
  const int m0 = blockIdx.x * BM;
  const int n0 = blockIdx.y * BN;

  floatx4 acc[4][4];
  #pragma unroll
  for (int i = 0; i < 4; ++i)
    #pragma unroll
    for (int j = 0; j < 4; ++j)
      acc[i][j] = floatx4{0.f, 0.f, 0.f, 0.f};

  floatx4 rb[4][2];
  auto ldb = [&](int k0) {
    #pragma unroll
    for (int it = 0; it < 4; ++it) {
      int linear = it * 256 + tid;
      int row = linear >> 3, pc = linear & 7;
      int c = pc ^ (row & 7);
      const float* pb = Wo + (size_t)(n0 + row) * HIDN + k0 + c * 8;
      rb[it][0] = *(const floatx4*)(pb);
      rb[it][1] = *(const floatx4*)(pb + 4);
    }
  };

  ldb(0);
  int kidx = 0;
  for (int k0 = 0; k0 < HIDN; k0 += BK, ++kidx) {
    const int buf = kidx & 1;
    #pragma unroll
    for (int it = 0; it < 4; ++it) {
      int linear = it * 256 + tid;
      int row = linear >> 3, pc = linear & 7;
      int c = pc ^ (row & 7);
      bf16x8 vb;
      #pragma unroll
      for (int j = 0; j < 4; ++j) {
        vb[j]     = (bf16_t)rb[it][0][j];
        vb[4 + j] = (bf16_t)rb[it][1][j];
      }
      *(bf16x8*)(Bs + buf * TILE + linear * 8) = vb;
      g2l16(ctx + (size_t)(m0 + row) * HIDN + k0 + c * 8, As + buf * TILE + linear * 8);
    }
    __syncthreads();
    if (k0 + BK < HIDN) ldb(k0 + BK);
    const bf16_t* Ab = As + buf * TILE;
    const bf16_t* Bb = Bs + buf * TILE;
    #pragma unroll
    for (int kk = 0; kk < BK; kk += 32) {
      bf16x8 af[4], bfr[4];
      #pragma unroll
      for (int t = 0; t < 4; ++t) {
        int pcr = ((kk >> 3) + lq) ^ (lr & 7);
        af[t]  = *(const bf16x8*)(Ab + (wm + t * 16 + lr) * BK + pcr * 8);
        bfr[t] = *(const bf16x8*)(Bb + (wn + t * 16 + lr) * BK + pcr * 8);
      }
      #pragma unroll
      for (int i = 0; i < 4; ++i)
        #pragma unroll
        for (int j = 0; j < 4; ++j)
          acc[i][j] = __builtin_amdgcn_mfma_f32_16x16x32_bf16(af[i], bfr[j], acc[i][j], 0, 0, 0);
    }
  }

  #pragma unroll
  for (int i = 0; i < 4; ++i)
    #pragma unroll
    for (int j = 0; j < 4; ++j)
      #pragma unroll
      for (int r = 0; r < 4; ++r) {
        int srow = m0 + wm + i * 16 + lq * 4 + r;
        int col  = n0 + wn + j * 16 + lr;
        out[(size_t)srow * HIDN + col] = acc[i][j][r];
      }
}

// ---------------- Flash attention v5: GQA-fused, 2 blocks/CU, kv-chunk 64 ----
// 512 blocks = 8 hkv x 64 q-tiles of 32 rows; each block serves BOTH heads of
// its kv-group (waves 0,1 -> head 2*hkv rows 0-31; waves 2,3 -> head 2*hkv+1).
// Complement mapping: blocks b and b+256 have t32 + t32' = 63 (balanced chunks).
// Wave-local softmax via S^T = MFMA(A=K, B=Q); P in wave-private swizzled LDS.
__global__ void __launch_bounds__(256, 2) attn_kernel(
    const bf16_t* __restrict__ qb, const bf16_t* __restrict__ kb,
    const bf16_t* __restrict__ vtb, bf16_t* __restrict__ ctx)
{
  __shared__ __align__(16) bf16_t Kb[2][64 * 128];   // [kv][d] swizzled, 16 KB each
  __shared__ __align__(16) bf16_t Vb[2][128 * 64];   // [d][kv] swizzled, 16 KB each
  __shared__ __align__(16) bf16_t Pb[4][16 * 64];    // wave-private P, swizzled

  const int tid  = threadIdx.x;
  const int lane = tid & 63, wave = tid >> 6;
  const int lr   = lane & 15, quad = lane >> 4;

  const int b = blockIdx.x;
  int hkv, t32;
  if (b < 256) { hkv = b >> 5; t32 = b & 31; }
  else         { int c = b - 256; hkv = c >> 5; t32 = 63 - (c & 31); }
  const int head = hkv * 2 + (wave >> 1);
  const int q0   = t32 * 32;
  const int nch  = (t32 >> 1) + 1;         // chunks of 64 kv
  const int qrow_g = q0 + ((wave & 1) << 4) + lr;

  const bf16_t* kbase  = kb  + (size_t)hkv * S_LEN * DH;
  const bf16_t* vtbase = vtb + (size_t)hkv * DH * S_LEN;
  const float scale = 0.08838834764831845f;  // 1/sqrt(128)
  bf16_t* pmine = &Pb[wave][0];

  // Q B-fragments (lane holds Q[qrow=lr][d=quad*8+j]) straight from global
  const bf16_t* qrp = qb + ((size_t)head * S_LEN + qrow_g) * DH;
  bf16x8 qf[4];
  #pragma unroll
  for (int kk = 0; kk < 4; ++kk)
    qf[kk] = *(const bf16x8*)(qrp + kk * 32 + quad * 8);

  auto stage = [&](int cc, int buf) {
    const int kv0 = cc * 64;
    #pragma unroll
    for (int it = 0; it < 4; ++it) {
      int linear = it * 256 + tid;           // 0..1023
      int krow = linear >> 4, kpc = linear & 15;
      int kc = kpc ^ (krow & 15);
      g2l16(kbase + (size_t)(kv0 + krow) * DH + kc * 8, &Kb[buf][linear * 8]);
      int vrow = linear >> 3, vpc = linear & 7;
      int vc = vpc ^ (vrow & 7);
      g2l16(vtbase + (size_t)vrow * S_LEN + kv0 + vc * 8, &Vb[buf][linear * 8]);
    }
  };

  float m_r = NEG_BIG, l_r = 0.f;
  floatx4 o[8];
  #pragma unroll
  for (int t = 0; t < 8; ++t) o[t] = floatx4{0.f, 0.f, 0.f, 0.f};

  stage(0, 0);

  for (int cc = 0; cc < nch; ++cc) {
    const int buf = cc & 1;
    __syncthreads();                         // staging cc landed; buf^1 free
    if (cc + 1 < nch) stage(cc + 1, buf ^ 1);
    const int kv0 = cc * 64;

    // S^T = K * Q^T : 4 kv tiles of 16, K-dim = d (4 x 32)
    floatx4 sacc[4];
    #pragma unroll
    for (int t = 0; t < 4; ++t) sacc[t] = floatx4{0.f, 0.f, 0.f, 0.f};
    #pragma unroll
    for (int kk = 0; kk < 4; ++kk) {
      const int pc = ((kk << 2) + quad) ^ lr;
      #pragma unroll
      for (int t = 0; t < 4; ++t) {
        bf16x8 kf = *(const bf16x8*)(&Kb[buf][(t * 16 + lr) * 128 + pc * 8]);
        sacc[t] = __builtin_amdgcn_mfma_f32_16x16x32_bf16(kf, qf[kk], sacc[t], 0, 0, 0);
      }
    }

    // causal mask (diagonal chunk only)
    if (cc == nch - 1) {
      #pragma unroll
      for (int t = 0; t < 4; ++t)
        #pragma unroll
        for (int r = 0; r < 4; ++r) {
          int kv = kv0 + t * 16 + quad * 4 + r;
          if (kv > qrow_g) sacc[t][r] = NEG_BIG;
        }
    }

    // row max (16 regs + 2 cross-quad shuffles), scale once
    float mx = sacc[0][0];
    #pragma unroll
    for (int t = 0; t < 4; ++t)
      #pragma unroll
      for (int r = 0; r < 4; ++r) mx = fmaxf(mx, sacc[t][r]);
    mx = fmaxf(mx, __shfl_xor(mx, 16, 64));
    mx = fmaxf(mx, __shfl_xor(mx, 32, 64));
    const float mn = fmaxf(m_r, mx * scale);
    const float alpha = __expf(m_r - mn);

    // p = exp(s*scale - mn); pack; wave-private swizzled LDS; row sum
    float lc = 0.f;
    #pragma unroll
    for (int t = 0; t < 4; ++t) {
      bf16x4 pk;
      #pragma unroll
      for (int r = 0; r < 4; ++r) {
        float p = __expf(fmaf(sacc[t][r], scale, -mn));
        lc += p;
        pk[r] = (bf16_t)p;
      }
      int pw = lr * 64 + (((2 * t + (quad >> 1)) ^ (lr & 7)) << 3) + (quad & 1) * 4;
      *(bf16x4*)(pmine + pw) = pk;
    }
    lc += __shfl_xor(lc, 16, 64);
    lc += __shfl_xor(lc, 32, 64);
    l_r = l_r * alpha + lc;
    m_r = mn;

    // O^T = O^T*alpha + V^T * P^T
    #pragma unroll
    for (int t = 0; t < 8; ++t)
      #pragma unroll
      for (int r = 0; r < 4; ++r) o[t][r] *= alpha;
    #pragma unroll
    for (int ks = 0; ks < 2; ++ks) {
      int prd = lr * 64 + (((ks * 4 + quad) ^ (lr & 7)) << 3);
      bf16x8 pf = *(const bf16x8*)(pmine + prd);
      #pragma unroll
      for (int t = 0; t < 8; ++t) {
        int pc = (ks * 4 + quad) ^ (lr & 7);
        bf16x8 vf = *(const bf16x8*)(&Vb[buf][(t * 16 + lr) * 64 + pc * 8]);
        o[t] = __builtin_amdgcn_mfma_f32_16x16x32_bf16(vf, pf, o[t], 0, 0, 0);
      }
    }
  }

  const float inv = 1.0f / l_r;
  bf16_t* crow = ctx + (size_t)qrow_g * HIDN + head * DH;
  #pragma unroll
  for (int t = 0; t < 8; ++t) {
    bf16x4 ov;
    #pragma unroll
    for (int r = 0; r < 4; ++r) ov[r] = (bf16_t)(o[t][r] * inv);
    *(bf16x4*)(crow + t * 16 + quad * 4) = ov;
  }
}

extern "C" void kernel_launch(void* const* d_in, const int* in_sizes, int n_in,
                              void* d_out, int out_size, void* d_ws, size_t ws_size,
                              hipStream_t stream)
{
  const float* xf   = (const float*)d_in[0];
  const float* Wqf  = (const float*)d_in[1];
  const float* Wkf  = (const float*)d_in[2];
  const float* Wvf  = (const float*)d_in[3];
  const float* Wof  = (const float*)d_in[4];
  const float* cosT = (const float*)d_in[5];
  const float* sinT = (const float*)d_in[6];
  float* out = (float*)d_out;

  char* ws = (char*)d_ws;
  const size_t MB = 1u << 20;
  bf16_t* qb  = (bf16_t*)(ws);              // 8 MB
  bf16_t* kb  = (bf16_t*)(ws + 8  * MB);    // 4 MB
  bf16_t* vtb = (bf16_t*)(ws + 12 * MB);    // 4 MB
  bf16_t* ctx = (bf16_t*)(ws + 16 * MB);    // 8 MB

  hipLaunchKernelGGL(gemm_qkv_kernel, dim3(16, 32), dim3(256), 0, stream,
                     xf, Wqf, Wkf, Wvf, qb, kb, vtb, cosT, sinT);
  hipLaunchKernelGGL(attn_kernel, dim3(512), dim3(256), 0, stream,
                     qb, kb, vtb, ctx);
  hipLaunchKernelGGL(gemm_out_kernel, dim3(16, 16), dim3(256), 0, stream,
                     ctx, Wof, out);
}

// Round 9
// 233.736 us; speedup vs baseline: 1.1378x; 1.1378x over previous
//
#include <hip/hip_runtime.h>
#include <hip/hip_bf16.h>

#define S_LEN 2048
#define HIDN  2048
#define NH    16
#define NKV   8
#define DH    128

typedef __bf16 bf16_t;
typedef __bf16 bf16x4 __attribute__((ext_vector_type(4)));
typedef __bf16 bf16x8 __attribute__((ext_vector_type(8)));
typedef float  floatx4 __attribute__((ext_vector_type(4)));

#define NEG_BIG (-1.0e30f)

#define BM 128
#define BN 128
#define BK 64

// async global->LDS, 16B per lane. LDS dest must be wave-uniform base + lane*16.
__device__ __forceinline__ void g2l16(const bf16_t* g, bf16_t* l) {
  __builtin_amdgcn_global_load_lds(
      (const __attribute__((address_space(1))) unsigned int*)g,
      (__attribute__((address_space(3))) unsigned int*)l, 16, 0, 0);
}

// ---------------- fused f32 -> bf16 conversion for all 5 inputs ----------------
__global__ void cvt_all_kernel(const float* __restrict__ x,  const float* __restrict__ wq,
                               const float* __restrict__ wk, const float* __restrict__ wv,
                               const float* __restrict__ wo,
                               bf16_t* __restrict__ xc,  bf16_t* __restrict__ wqc,
                               bf16_t* __restrict__ wkc, bf16_t* __restrict__ wvc,
                               bf16_t* __restrict__ woc)
{
  const int b = blockIdx.x;
  const float* src; bf16_t* dst; int off;
  if      (b < 1024) { src = x;  dst = xc;  off = b; }
  else if (b < 2048) { src = wq; dst = wqc; off = b - 1024; }
  else if (b < 2560) { src = wk; dst = wkc; off = b - 2048; }
  else if (b < 3072) { src = wv; dst = wvc; off = b - 2560; }
  else               { src = wo; dst = woc; off = b - 3072; }
  const int base = off * 4096 + threadIdx.x;
  #pragma unroll
  for (int i = 0; i < 16; ++i)
    dst[base + i * 256] = (bf16_t)src[base + i * 256];
}

// ---------------- GEMM tile (m97: global_load_lds staging + XOR swizzle) ------
__device__ __forceinline__ void gemm_tile(
    const bf16_t* __restrict__ A, const bf16_t* __restrict__ Bt,
    int K, int m0, int n0, floatx4 acc[4][4], bf16_t* As, bf16_t* Bs)
{
  const int tid  = threadIdx.x;
  const int lane = tid & 63;
  const int wave = tid >> 6;
  const int wm = (wave & 1) << 6;
  const int wn = (wave >> 1) << 6;
  const int lr = lane & 15;
  const int lq = lane >> 4;

  #pragma unroll
  for (int i = 0; i < 4; ++i)
    #pragma unroll
    for (int j = 0; j < 4; ++j)
      acc[i][j] = floatx4{0.f, 0.f, 0.f, 0.f};

  for (int k0 = 0; k0 < K; k0 += BK) {
    #pragma unroll
    for (int it = 0; it < 4; ++it) {
      int linear = it * 256 + tid;
      int row = linear >> 3;
      int pc  = linear & 7;
      int c   = pc ^ (row & 7);
      g2l16(A  + (size_t)(m0 + row) * K + k0 + c * 8, As + linear * 8);
      g2l16(Bt + (size_t)(n0 + row) * K + k0 + c * 8, Bs + linear * 8);
    }
    __syncthreads();
    #pragma unroll
    for (int kk = 0; kk < BK; kk += 32) {
      bf16x8 af[4], bfr[4];
      #pragma unroll
      for (int t = 0; t < 4; ++t) {
        int pcr = ((kk >> 3) + lq) ^ (lr & 7);
        af[t]  = *(const bf16x8*)(As + (wm + t * 16 + lr) * BK + pcr * 8);
        bfr[t] = *(const bf16x8*)(Bs + (wn + t * 16 + lr) * BK + pcr * 8);
      }
      #pragma unroll
      for (int i = 0; i < 4; ++i)
        #pragma unroll
        for (int j = 0; j < 4; ++j)
          acc[i][j] = __builtin_amdgcn_mfma_f32_16x16x32_bf16(af[i], bfr[j], acc[i][j], 0, 0, 0);
    }
    __syncthreads();
  }
}

// QKV GEMM with fused RoPE (q,k heads) and V-transpose (v heads) epilogue.
__global__ void __launch_bounds__(256, 2) gemm_qkv_kernel(
    const bf16_t* __restrict__ x, const bf16_t* __restrict__ Wq,
    const bf16_t* __restrict__ Wk, const bf16_t* __restrict__ Wv,
    bf16_t* __restrict__ qb, bf16_t* __restrict__ kb, bf16_t* __restrict__ vtb,
    const float* __restrict__ cosT, const float* __restrict__ sinT)
{
  __shared__ __align__(16) bf16_t As[BM * BK];
  __shared__ __align__(16) bf16_t Bs[BN * BK];
  __shared__ __align__(16) bf16_t Epi[128 * 132];   // epilogue exchange tile
  const int tid = threadIdx.x;
  const int m0 = blockIdx.x * BM;
  const int nt = blockIdx.y;
  const bf16_t* Bt;
  int hbase;
  if (nt < 16)      { Bt = Wq + (size_t)nt * 128 * HIDN;        hbase = nt; }
  else if (nt < 24) { Bt = Wk + (size_t)(nt - 16) * 128 * HIDN; hbase = nt - 16; }
  else              { Bt = Wv + (size_t)(nt - 24) * 128 * HIDN; hbase = nt - 24; }

  floatx4 acc[4][4];
  gemm_tile(x, Bt, HIDN, m0, 0, acc, As, Bs);

  const int lane = tid & 63, wave = tid >> 6;
  const int wm = (wave & 1) << 6, wn = (wave >> 1) << 6;
  const int lr = lane & 15, lq = lane >> 4;
  #pragma unroll
  for (int i = 0; i < 4; ++i)
    #pragma unroll
    for (int j = 0; j < 4; ++j)
      #pragma unroll
      for (int r = 0; r < 4; ++r) {
        int row = wm + i * 16 + lq * 4 + r;
        int col = wn + j * 16 + lr;
        Epi[row * 132 + col] = (bf16_t)acc[i][j][r];
      }
  __syncthreads();

  if (nt < 24) {
    // RoPE: out[d] = a*cos - b*sin; out[d+64] = b*cos + a*sin  (cos[d+64]==cos[d])
    bf16_t* outp = (nt < 16) ? qb : kb;
    #pragma unroll
    for (int u = 0; u < 32; ++u) {
      int idx = u * 256 + tid;              // 0..8191
      int dd = idx & 63, s = idx >> 6;
      float a = (float)Epi[s * 132 + dd];
      float b = (float)Epi[s * 132 + dd + 64];
      int sg = m0 + s;
      float cv = cosT[sg * DH + dd];
      float sv = sinT[sg * DH + dd];
      size_t off = ((size_t)hbase * S_LEN + sg) * DH;
      outp[off + dd]      = (bf16_t)(a * cv - b * sv);
      outp[off + dd + 64] = (bf16_t)(b * cv + a * sv);
    }
  } else {
    // V transpose: vt[hkv][d][s]
    bf16_t* dst = vtb + (size_t)hbase * DH * S_LEN;
    #pragma unroll
    for (int u = 0; u < 64; ++u) {
      int idx = u * 256 + tid;              // 0..16383
      int sl = idx & 127, d = idx >> 7;
      dst[(size_t)d * S_LEN + m0 + sl] = Epi[sl * 132 + d];
    }
  }
}

// out = ctx[2048,2048] * Wo^T -> d_out (f32).
// ONLY change this round: BM=64 x BN=128 tiles -> 512 blocks = 2 blocks/CU so
// a co-resident block's MFMA hides the staging-barrier drain (m114 overlap).
__global__ void __launch_bounds__(256, 2) gemm_out_kernel(
    const bf16_t* __restrict__ ctx, const bf16_t* __restrict__ Wo,
    float* __restrict__ out)
{
  __shared__ __align__(16) bf16_t As[64 * BK];    // 8 KB
  __shared__ __align__(16) bf16_t Bs[128 * BK];   // 16 KB
  const int tid = threadIdx.x;
  const int lane = tid & 63, wave = tid >> 6;
  const int wm = (wave & 1) << 5;                 // 0 / 32
  const int wn = (wave >> 1) << 6;                // 0 / 64
  const int lr = lane & 15, lq = lane >> 4;
  const int m0 = blockIdx.x * 64;
  const int n0 = blockIdx.y * 128;

  floatx4 acc[2][4];
  #pragma unroll
  for (int i = 0; i < 2; ++i)
    #pragma unroll
    for (int j = 0; j < 4; ++j)
      acc[i][j] = floatx4{0.f, 0.f, 0.f, 0.f};

  for (int k0 = 0; k0 < HIDN; k0 += BK) {
    #pragma unroll
    for (int it = 0; it < 2; ++it) {              // A: 64 rows x 8 chunks
      int linear = it * 256 + tid;
      int row = linear >> 3, pc = linear & 7;
      int c = pc ^ (row & 7);
      g2l16(ctx + (size_t)(m0 + row) * HIDN + k0 + c * 8, As + linear * 8);
    }
    #pragma unroll
    for (int it = 0; it < 4; ++it) {              // B: 128 rows x 8 chunks
      int linear = it * 256 + tid;
      int row = linear >> 3, pc = linear & 7;
      int c = pc ^ (row & 7);
      g2l16(Wo + (size_t)(n0 + row) * HIDN + k0 + c * 8, Bs + linear * 8);
    }
    __syncthreads();
    #pragma unroll
    for (int kk = 0; kk < BK; kk += 32) {
      bf16x8 af[2], bfr[4];
      int pcr = ((kk >> 3) + lq) ^ (lr & 7);
      #pragma unroll
      for (int t = 0; t < 2; ++t)
        af[t]  = *(const bf16x8*)(As + (wm + t * 16 + lr) * BK + pcr * 8);
      #pragma unroll
      for (int t = 0; t < 4; ++t)
        bfr[t] = *(const bf16x8*)(Bs + (wn + t * 16 + lr) * BK + pcr * 8);
      #pragma unroll
      for (int i = 0; i < 2; ++i)
        #pragma unroll
        for (int j = 0; j < 4; ++j)
          acc[i][j] = __builtin_amdgcn_mfma_f32_16x16x32_bf16(af[i], bfr[j], acc[i][j], 0, 0, 0);
    }
    __syncthreads();
  }

  #pragma unroll
  for (int i = 0; i < 2; ++i)
    #pragma unroll
    for (int j = 0; j < 4; ++j)
      #pragma unroll
      for (int r = 0; r < 4; ++r) {
        int srow = m0 + wm + i * 16 + lq * 4 + r;
        int col  = n0 + wn + j * 16 + lr;
        out[(size_t)srow * HIDN + col] = acc[i][j][r];
      }
}

// ---------------- Flash attention v4 (R7, measured 59.5 us) ----------------
__global__ void __launch_bounds__(256, 2) attn_kernel(
    const bf16_t* __restrict__ qb, const bf16_t* __restrict__ kb,
    const bf16_t* __restrict__ vtb, bf16_t* __restrict__ ctx)
{
  __shared__ __align__(16) bf16_t Kb[2][64 * 128];   // [kv][d] swizzled, 16 KB each
  __shared__ __align__(16) bf16_t Vb[2][128 * 64];   // [d][kv] swizzled, 16 KB each
  __shared__ __align__(16) bf16_t Pb[4][16 * 64];    // wave-private P, swizzled

  const int tid  = threadIdx.x;
  const int lane = tid & 63, wave = tid >> 6;
  const int lr   = lane & 15, quad = lane >> 4;

  const int b = blockIdx.x;
  int h, qt;
  if (b < 256) { h = b >> 5;              qt = b & 31; }
  else         { int c = b - 256; h = 8 + (c >> 5); qt = 31 - (c & 31); }
  const int hkv = h >> 1;
  const int q0  = qt * 64;
  const int nch = qt + 1;                  // chunks of 64 kv
  const int qrow_g = q0 + wave * 16 + lr;  // this thread's q-row

  const bf16_t* kbase  = kb  + (size_t)hkv * S_LEN * DH;
  const bf16_t* vtbase = vtb + (size_t)hkv * DH * S_LEN;
  const float scale = 0.08838834764831845f;  // 1/sqrt(128)
  bf16_t* pmine = &Pb[wave][0];

  // Q B-fragments (lane holds Q[qrow=lr][d=quad*8+j]) straight from global
  const bf16_t* qrp = qb + ((size_t)h * S_LEN + qrow_g) * DH;
  bf16x8 qf[4];
  #pragma unroll
  for (int kk = 0; kk < 4; ++kk)
    qf[kk] = *(const bf16x8*)(qrp + kk * 32 + quad * 8);

  auto stage = [&](int cc, int buf) {
    const int kv0 = cc * 64;
    #pragma unroll
    for (int it = 0; it < 4; ++it) {
      int linear = it * 256 + tid;           // 0..1023
      int krow = linear >> 4, kpc = linear & 15;
      int kc = kpc ^ (krow & 15);
      g2l16(kbase + (size_t)(kv0 + krow) * DH + kc * 8, &Kb[buf][linear * 8]);
      int vrow = linear >> 3, vpc = linear & 7;
      int vc = vpc ^ (vrow & 7);
      g2l16(vtbase + (size_t)vrow * S_LEN + kv0 + vc * 8, &Vb[buf][linear * 8]);
    }
  };

  float m_r = NEG_BIG, l_r = 0.f;
  floatx4 o[8];
  #pragma unroll
  for (int t = 0; t < 8; ++t) o[t] = floatx4{0.f, 0.f, 0.f, 0.f};

  stage(0, 0);

  for (int cc = 0; cc < nch; ++cc) {
    const int buf = cc & 1;
    __syncthreads();                         // staging cc landed; buf^1 free
    if (cc + 1 < nch) stage(cc + 1, buf ^ 1);
    const int kv0 = cc * 64;

    // S^T = K * Q^T : 4 kv tiles of 16, K-dim = d (4 x 32)
    floatx4 sacc[4];
    #pragma unroll
    for (int t = 0; t < 4; ++t) sacc[t] = floatx4{0.f, 0.f, 0.f, 0.f};
    #pragma unroll
    for (int kk = 0; kk < 4; ++kk) {
      const int pc = ((kk << 2) + quad) ^ lr;
      #pragma unroll
      for (int t = 0; t < 4; ++t) {
        bf16x8 kf = *(const bf16x8*)(&Kb[buf][(t * 16 + lr) * 128 + pc * 8]);
        sacc[t] = __builtin_amdgcn_mfma_f32_16x16x32_bf16(kf, qf[kk], sacc[t], 0, 0, 0);
      }
    }

    // causal mask (diagonal chunk only)
    if (cc == nch - 1) {
      #pragma unroll
      for (int t = 0; t < 4; ++t)
        #pragma unroll
        for (int r = 0; r < 4; ++r) {
          int kv = kv0 + t * 16 + quad * 4 + r;
          if (kv > qrow_g) sacc[t][r] = NEG_BIG;
        }
    }

    // row max (16 regs + 2 cross-quad shuffles), then scale once
    float mx = sacc[0][0];
    #pragma unroll
    for (int t = 0; t < 4; ++t)
      #pragma unroll
      for (int r = 0; r < 4; ++r) mx = fmaxf(mx, sacc[t][r]);
    mx = fmaxf(mx, __shfl_xor(mx, 16, 64));
    mx = fmaxf(mx, __shfl_xor(mx, 32, 64));
    const float mn = fmaxf(m_r, mx * scale);
    const float alpha = __expf(m_r - mn);

    // p = exp(s*scale - mn); pack; wave-private swizzled LDS; row sum
    float lc = 0.f;
    #pragma unroll
    for (int t = 0; t < 4; ++t) {
      bf16x4 pk;
      #pragma unroll
      for (int r = 0; r < 4; ++r) {
        float p = __expf(fmaf(sacc[t][r], scale, -mn));
        lc += p;
        pk[r] = (bf16_t)p;
      }
      int pw = lr * 64 + (((2 * t + (quad >> 1)) ^ (lr & 7)) << 3) + (quad & 1) * 4;
      *(bf16x4*)(pmine + pw) = pk;
    }
    lc += __shfl_xor(lc, 16, 64);
    lc += __shfl_xor(lc, 32, 64);
    l_r = l_r * alpha + lc;
    m_r = mn;

    // O^T = O^T*alpha + V^T * P^T
    #pragma unroll
    for (int t = 0; t < 8; ++t)
      #pragma unroll
      for (int r = 0; r < 4; ++r) o[t][r] *= alpha;
    #pragma unroll
    for (int ks = 0; ks < 2; ++ks) {
      int prd = lr * 64 + (((ks * 4 + quad) ^ (lr & 7)) << 3);
      bf16x8 pf = *(const bf16x8*)(pmine + prd);
      #pragma unroll
      for (int t = 0; t < 8; ++t) {
        int pc = (ks * 4 + quad) ^ (lr & 7);
        bf16x8 vf = *(const bf16x8*)(&Vb[buf][(t * 16 + lr) * 64 + pc * 8]);
        o[t] = __builtin_amdgcn_mfma_f32_16x16x32_bf16(vf, pf, o[t], 0, 0, 0);
      }
    }
  }

  const float inv = 1.0f / l_r;
  bf16_t* crow = ctx + (size_t)qrow_g * HIDN + h * DH;
  #pragma unroll
  for (int t = 0; t < 8; ++t) {
    bf16x4 ov;
    #pragma unroll
    for (int r = 0; r < 4; ++r) ov[r] = (bf16_t)(o[t][r] * inv);
    *(bf16x4*)(crow + t * 16 + quad * 4) = ov;
  }
}

extern "C" void kernel_launch(void* const* d_in, const int* in_sizes, int n_in,
                              void* d_out, int out_size, void* d_ws, size_t ws_size,
                              hipStream_t stream)
{
  const float* xf   = (const float*)d_in[0];
  const float* Wqf  = (const float*)d_in[1];
  const float* Wkf  = (const float*)d_in[2];
  const float* Wvf  = (const float*)d_in[3];
  const float* Wof  = (const float*)d_in[4];
  const float* cosT = (const float*)d_in[5];
  const float* sinT = (const float*)d_in[6];
  float* out = (float*)d_out;

  char* ws = (char*)d_ws;
  const size_t MB = 1u << 20;
  bf16_t* xc  = (bf16_t*)(ws);              // 8 MB
  bf16_t* Wqc = (bf16_t*)(ws + 8  * MB);    // 8 MB
  bf16_t* Wkc = (bf16_t*)(ws + 16 * MB);    // 4 MB
  bf16_t* Wvc = (bf16_t*)(ws + 20 * MB);    // 4 MB
  bf16_t* Woc = (bf16_t*)(ws + 24 * MB);    // 8 MB
  bf16_t* qb  = (bf16_t*)(ws + 32 * MB);    // 8 MB
  bf16_t* kb  = (bf16_t*)(ws + 40 * MB);    // 4 MB
  bf16_t* vtb = (bf16_t*)(ws + 44 * MB);    // 4 MB
  bf16_t* ctx = (bf16_t*)(ws + 48 * MB);    // 8 MB

  hipLaunchKernelGGL(cvt_all_kernel, dim3(4096), dim3(256), 0, stream,
                     xf, Wqf, Wkf, Wvf, Wof, xc, Wqc, Wkc, Wvc, Woc);
  hipLaunchKernelGGL(gemm_qkv_kernel, dim3(16, 32), dim3(256), 0, stream,
                     xc, Wqc, Wkc, Wvc, qb, kb, vtb, cosT, sinT);
  hipLaunchKernelGGL(attn_kernel, dim3(512), dim3(256), 0, stream,
                     qb, kb, vtb, ctx);
  hipLaunchKernelGGL(gemm_out_kernel, dim3(32, 16), dim3(256), 0, stream,
                     ctx, Woc, out);
}